// Round 1
// baseline (2050.599 us; speedup 1.0000x reference)
//
#include <hip/hip_runtime.h>
#include <hip/hip_bf16.h>

typedef _Float16 f16;
typedef _Float16 f16x8 __attribute__((ext_vector_type(8)));
typedef float    f32x4 __attribute__((ext_vector_type(4)));
typedef float    f32x8 __attribute__((ext_vector_type(8)));

__device__ __forceinline__ float silu_f(float x) {
    return x / (1.0f + __expf(-x));
}

// ---------------------------------------------------------------------------
// Weight prep: B1T[l][256][64] (node-GEMM B, P|Q columns), W2T[l][128][128],
// W3T[l][64][128] (transposed for MFMA B-fragments), w1c[l][128] (dist2 row).
// ---------------------------------------------------------------------------
__global__ void prep_kernel(const float* __restrict__ W1, const float* __restrict__ W2,
                            const float* __restrict__ W3, f16* __restrict__ B1T,
                            f16* __restrict__ W2T, f16* __restrict__ W3T,
                            float* __restrict__ w1c, int L, int total) {
    int idx = blockIdx.x * 256 + threadIdx.x;
    if (idx >= total) return;
    const int per = 16384 + 16384 + 8192 + 128;
    int l = idx / per, r = idx % per;
    const float* W1l = W1 + (size_t)l * 126 * 128;
    if (r < 16384) {                       // B1T: c in [0,256), k in [0,64)
        int c = r >> 6, k = r & 63;
        float v;
        if (c < 128) v = W1l[k * 128 + c];                       // P: xi @ W1[0:64]
        else v = (k >= 3) ? W1l[(64 + k - 3) * 128 + (c - 128)]  // Q: xj[3:] @ W1[64:125]
                          : 0.0f;
        B1T[(size_t)l * 16384 + r] = (f16)v;
    } else if (r < 32768) {                // W2T[n][k] = W2[k][n]
        int q = r - 16384, n = q >> 7, k = q & 127;
        W2T[(size_t)l * 16384 + q] = (f16)W2[(size_t)l * 16384 + k * 128 + n];
    } else if (r < 40960) {                // W3T[n][k] = W3[k][n]
        int q = r - 32768, n = q >> 7, k = q & 127;
        W3T[(size_t)l * 8192 + q] = (f16)W3[(size_t)l * 8192 + k * 64 + n];
    } else {                               // w1c = W1[125][:]
        int c = r - 40960;
        w1c[l * 128 + c] = W1l[125 * 128 + c];
    }
}

// ---------------------------------------------------------------------------
// CSR build: histogram over dst, 2-level exclusive scan, counting-sort scatter
// ---------------------------------------------------------------------------
__global__ void hist_kernel(const int* __restrict__ ei, int* __restrict__ deg, int E) {
    int i = blockIdx.x * 256 + threadIdx.x;
    if (i < E) atomicAdd(&deg[ei[E + i]], 1);
}

__global__ void scan_part(const int* __restrict__ deg, int* __restrict__ bsum, int N) {
    __shared__ int red[256];
    int t = threadIdx.x;
    int i = blockIdx.x * 256 + t;
    red[t] = (i < N) ? deg[i] : 0;
    __syncthreads();
    for (int s = 128; s > 0; s >>= 1) {
        if (t < s) red[t] += red[t + s];
        __syncthreads();
    }
    if (t == 0) bsum[blockIdx.x] = red[0];
}

__global__ void scan_mid(const int* __restrict__ bsum, int* __restrict__ boff, int nb) {
    __shared__ int sm[512];
    int t = threadIdx.x;
    int v = (t < nb) ? bsum[t] : 0;
    sm[t] = v;
    __syncthreads();
    for (int off = 1; off < 512; off <<= 1) {
        int a = (t >= off) ? sm[t - off] : 0;
        __syncthreads();
        sm[t] += a;
        __syncthreads();
    }
    if (t < nb) boff[t] = sm[t] - v;   // exclusive
}

__global__ void scan_final(const int* __restrict__ deg, const int* __restrict__ boff,
                           int* __restrict__ row_start, int N) {
    __shared__ int sm[256];
    int t = threadIdx.x;
    int i = blockIdx.x * 256 + t;
    int v = (i < N) ? deg[i] : 0;
    sm[t] = v;
    __syncthreads();
    for (int off = 1; off < 256; off <<= 1) {
        int a = (t >= off) ? sm[t - off] : 0;
        __syncthreads();
        sm[t] += a;
        __syncthreads();
    }
    if (i < N) row_start[i] = boff[blockIdx.x] + sm[t] - v;
}

__global__ void scatter_kernel(const int* __restrict__ ei, const int* __restrict__ row_start,
                               int* __restrict__ cursor, int* __restrict__ srcs,
                               int* __restrict__ dsts, int E) {
    int i = blockIdx.x * 256 + threadIdx.x;
    if (i < E) {
        int d = ei[E + i];
        int p = row_start[d] + atomicAdd(&cursor[d], 1);
        srcs[p] = ei[i];
        dsts[p] = d;
    }
}

// ---------------------------------------------------------------------------
// Node kernel: PQ[n][0:128] = x[n]@W1a + b1 ; PQ[n][128:256] = x[n,3:]@W1b
// Also emits C[n] = coords for dist2. MFMA 16x16x32 f16, 64-node tiles.
// ---------------------------------------------------------------------------
__global__ __launch_bounds__(256, 3) void node_kernel(
    const float* __restrict__ x, const f16* __restrict__ B1T,
    const float* __restrict__ b1, f16* __restrict__ PQ,
    float4* __restrict__ C, int N, int ntiles) {
    __shared__ f16 b1t[256 * 72];   // padded stride 72 (2-way bank aliasing only)
    const int tid = threadIdx.x;
    const int w = tid >> 6, lane = tid & 63, lm = lane & 15, kg = lane >> 4;

    for (int i = tid; i < 256 * 64; i += 256)
        b1t[(i >> 6) * 72 + (i & 63)] = B1T[i];
    __syncthreads();

    for (int tile = blockIdx.x; tile < ntiles; tile += gridDim.x) {
        const int base = tile * 64;
        int ar = base + w * 16 + lm;
        if (ar >= N) ar = N - 1;

        f16x8 afrag[2];
#pragma unroll
        for (int ks = 0; ks < 2; ks++) {
            f32x8 v = *(const f32x8*)(x + (size_t)ar * 64 + ks * 32 + kg * 8);
            f16x8 h;
#pragma unroll
            for (int j = 0; j < 8; j++) h[j] = (f16)v[j];
            afrag[ks] = h;
        }

        f32x4 acc[16];
#pragma unroll
        for (int nb = 0; nb < 16; nb++) acc[nb] = (f32x4){0.f, 0.f, 0.f, 0.f};
#pragma unroll
        for (int ks = 0; ks < 2; ks++)
#pragma unroll
            for (int nb = 0; nb < 16; nb++) {
                f16x8 b = *(const f16x8*)&b1t[(nb * 16 + lm) * 72 + ks * 32 + kg * 8];
                acc[nb] = __builtin_amdgcn_mfma_f32_16x16x32_f16(afrag[ks], b, acc[nb], 0, 0, 0);
            }

#pragma unroll
        for (int nb = 0; nb < 16; nb++) {
            int col = nb * 16 + lm;
            float bias = (col < 128) ? b1[col] : 0.0f;
#pragma unroll
            for (int reg = 0; reg < 4; reg++) {
                int orow = base + w * 16 + kg * 4 + reg;
                if (orow < N) PQ[(size_t)orow * 256 + col] = (f16)(acc[nb][reg] + bias);
            }
        }
        if (tid < 64) {
            int n = base + tid;
            if (n < N) {
                const float* xr = x + (size_t)n * 64;
                C[n] = make_float4(xr[0], xr[1], xr[2], 0.0f);
            }
        }
    }
}

// ---------------------------------------------------------------------------
// Edge kernel: per 64-edge (dst-sorted) tile:
//   h1 = silu(P[dst]+Q[src]+dist2*w1c)  -> built directly in A-frag registers
//   h2 = silu(h1@W2 + b2)               -> W2T in swizzled LDS
//   m  = silu(h2@W3 + b3)               -> W3T via L1 (16KB, hot)
//   segmented sum of m over sorted dst  -> few atomics per distinct dst
// ---------------------------------------------------------------------------
__global__ __launch_bounds__(256, 3) void edge_kernel(
    const f16* __restrict__ PQ, const float4* __restrict__ C,
    const int* __restrict__ srcs, const int* __restrict__ dsts,
    const f16* __restrict__ W2T, const f16* __restrict__ W3T,
    const float* __restrict__ w1c, const float* __restrict__ b2,
    const float* __restrict__ b3, float* __restrict__ xout,
    int E, int ntiles) {
    __shared__ f16 w2t[128 * 128];      // 32KB, XOR-swizzled
    __shared__ float region[64 * 64];   // 16KB: m tile; also h2 transpose buffers

    const int tid = threadIdx.x;
    const int w = tid >> 6, lane = tid & 63, lm = lane & 15, kg = lane >> 4;

    for (int i = tid; i < 128 * 128; i += 256) {
        int n = i >> 7, k = i & 127;
        w2t[n * 128 + (((k >> 3) ^ (n & 15)) << 3) + (k & 7)] = W2T[i];
    }
    __syncthreads();

    f16* tbuf = ((f16*)region) + w * (16 * 72);   // wave-private 16x72 f16 slice

    for (int tile = blockIdx.x; tile < ntiles; tile += gridDim.x) {
        const int base = tile * 64;
        const int rows = min(64, E - base);

        int er = base + w * 16 + lm;
        if (er >= E) er = E - 1;
        const int s = srcs[er], d = dsts[er];
        float4 cs = C[s], cd = C[d];
        float dx = cs.x - cd.x, dy = cs.y - cd.y, dz = cs.z - cd.z;
        float dist2 = dx * dx + dy * dy + dz * dz;

        // ---- h1 directly into A fragments (16B gathers per lane) ----
        f16x8 afrag[4];
        const f16* pd = PQ + (size_t)d * 256;
        const f16* ps = PQ + (size_t)s * 256 + 128;
#pragma unroll
        for (int ks = 0; ks < 4; ks++) {
            int off = ks * 32 + kg * 8;
            f16x8 p = *(const f16x8*)(pd + off);
            f16x8 q = *(const f16x8*)(ps + off);
            f32x8 wv = *(const f32x8*)(w1c + off);
            f16x8 h;
#pragma unroll
            for (int j = 0; j < 8; j++) {
                float v = (float)p[j] + (float)q[j] + dist2 * wv[j];
                h[j] = (f16)silu_f(v);
            }
            afrag[ks] = h;
        }

        // ---- GEMM1: h1 @ W2 ----
        f32x4 acc1[8];
#pragma unroll
        for (int nb = 0; nb < 8; nb++) acc1[nb] = (f32x4){0.f, 0.f, 0.f, 0.f};
#pragma unroll
        for (int ks = 0; ks < 4; ks++)
#pragma unroll
            for (int nb = 0; nb < 8; nb++) {
                int n = nb * 16 + lm;
                f16x8 b = *(const f16x8*)&w2t[n * 128 + (((ks * 4 + kg) ^ (n & 15)) << 3)];
                acc1[nb] = __builtin_amdgcn_mfma_f32_16x16x32_f16(afrag[ks], b, acc1[nb], 0, 0, 0);
            }

        // ---- silu+b2, transpose via wave-private LDS, GEMM2: h2 @ W3 ----
        f32x4 acc2[4];
#pragma unroll
        for (int nb = 0; nb < 4; nb++) acc2[nb] = (f32x4){0.f, 0.f, 0.f, 0.f};
#pragma unroll
        for (int kh = 0; kh < 2; kh++) {
#pragma unroll
            for (int nb2 = 0; nb2 < 4; nb2++) {
                int nb = kh * 4 + nb2;
                int col = nb * 16 + lm;
                float bias = b2[col];
#pragma unroll
                for (int reg = 0; reg < 4; reg++)
                    tbuf[(kg * 4 + reg) * 72 + (col - kh * 64)] =
                        (f16)silu_f(acc1[nb][reg] + bias);
            }
#pragma unroll
            for (int kk = 0; kk < 2; kk++) {
                f16x8 a2 = *(const f16x8*)&tbuf[lm * 72 + kk * 32 + kg * 8];
#pragma unroll
                for (int nb2 = 0; nb2 < 4; nb2++) {
                    f16x8 b = *(const f16x8*)(W3T + (size_t)(nb2 * 16 + lm) * 128 +
                                              kh * 64 + kk * 32 + kg * 8);
                    acc2[nb2] = __builtin_amdgcn_mfma_f32_16x16x32_f16(a2, b, acc2[nb2], 0, 0, 0);
                }
            }
        }
        __syncthreads();   // all waves done reading their tbuf slices

        // ---- m = silu(acc2 + b3) into LDS [64][64] ----
#pragma unroll
        for (int nb2 = 0; nb2 < 4; nb2++) {
            int col = nb2 * 16 + lm;
            float bias = b3[col];
#pragma unroll
            for (int reg = 0; reg < 4; reg++) {
                int r = w * 16 + kg * 4 + reg;
                region[r * 64 + col] = silu_f(acc2[nb2][reg] + bias);
            }
        }
        __syncthreads();

        // ---- segmented reduction over sorted dst ----
        {
            const int ch = tid & 63;
            const int rg = tid >> 6;
            for (int it = 0; it < 16; it++) {
                int r = it * 4 + rg;
                if (r < rows) {
                    int dr = dsts[base + r];
                    bool head = (r == 0) || (dsts[base + r - 1] != dr);
                    if (head) {
                        float sum = region[r * 64 + ch];
                        int rr = r + 1;
                        while (rr < rows && dsts[base + rr] == dr) {
                            sum += region[rr * 64 + ch];
                            rr++;
                        }
                        atomicAdd(&xout[(size_t)dr * 64 + ch], sum);
                    }
                }
            }
        }
        __syncthreads();   // scatter reads done before next tile reuses region
    }
}

// ---------------------------------------------------------------------------
// Pooling: per-graph add/mean/max over contiguous node ranges (batch = n*G//N)
// ---------------------------------------------------------------------------
__global__ void pool_kernel(const float* __restrict__ xf, const float* __restrict__ u,
                            float* __restrict__ pooled, int N, int G) {
    int g = blockIdx.x;
    int t = threadIdx.x;
    int ch = t & 63, sub = t >> 6;
    long long n0 = ((long long)g * N + G - 1) / G;
    long long n1 = ((long long)(g + 1) * N + G - 1) / G;
    float sm = 0.f, mx = -3.0e38f;
    for (long long n = n0 + sub; n < n1; n += 4) {
        float v = xf[n * 64 + ch];
        sm += v;
        mx = fmaxf(mx, v);
    }
    __shared__ float ssum[256], smax[256];
    ssum[t] = sm;
    smax[t] = mx;
    __syncthreads();
    if (sub == 0) {
        float a = ssum[ch] + ssum[64 + ch] + ssum[128 + ch] + ssum[192 + ch];
        float m = fmaxf(fmaxf(smax[ch], smax[64 + ch]), fmaxf(smax[128 + ch], smax[192 + ch]));
        float cnt = (float)(n1 - n0);
        pooled[g * 194 + ch] = a;
        pooled[g * 194 + 64 + ch] = a / fmaxf(cnt, 1.f);
        pooled[g * 194 + 128 + ch] = m;
    }
    if (t == 0) {
        pooled[g * 194 + 192] = u[g * 2];
        pooled[g * 194 + 193] = u[g * 2 + 1];
    }
}

// ---------------------------------------------------------------------------
// Readout head (fp32): [G,194]@[194,64] silu, @[64,64] silu, @[64,2]
// ---------------------------------------------------------------------------
__global__ void head_kernel(const float* __restrict__ pooled,
                            const float* __restrict__ LW1, const float* __restrict__ Lb1,
                            const float* __restrict__ LW2, const float* __restrict__ Lb2,
                            const float* __restrict__ LW3, const float* __restrict__ Lb3,
                            float* __restrict__ out, int G) {
    int g = blockIdx.x, t = threadIdx.x;
    __shared__ float pl[194];
    __shared__ float hl[64];
    for (int k = t; k < 194; k += 64) pl[k] = pooled[g * 194 + k];
    __syncthreads();
    float a = Lb1[t];
    for (int k = 0; k < 194; k++) a += pl[k] * LW1[k * 64 + t];
    a = silu_f(a);
    hl[t] = a;
    __syncthreads();
    float b = Lb2[t];
    for (int k = 0; k < 64; k++) b += hl[k] * LW2[k * 64 + t];
    b = silu_f(b);
    __syncthreads();
    hl[t] = b;
    __syncthreads();
    if (t < 2) {
        float c = Lb3[t];
        for (int k = 0; k < 64; k++) c += hl[k] * LW3[k * 2 + t];
        out[g * 2 + t] = c;
    }
}

// ---------------------------------------------------------------------------
extern "C" void kernel_launch(void* const* d_in, const int* in_sizes, int n_in,
                              void* d_out, int out_size, void* d_ws, size_t ws_size,
                              hipStream_t stream) {
    const float* x   = (const float*)d_in[0];
    const float* u   = (const float*)d_in[1];
    const int*   ei  = (const int*)d_in[2];
    const float* W1  = (const float*)d_in[4];
    const float* b1  = (const float*)d_in[5];
    const float* W2  = (const float*)d_in[6];
    const float* b2  = (const float*)d_in[7];
    const float* W3  = (const float*)d_in[8];
    const float* b3  = (const float*)d_in[9];
    const float* LW1 = (const float*)d_in[10];
    const float* Lb1 = (const float*)d_in[11];
    const float* LW2 = (const float*)d_in[12];
    const float* Lb2 = (const float*)d_in[13];
    const float* LW3 = (const float*)d_in[14];
    const float* Lb3 = (const float*)d_in[15];

    const int N = in_sizes[0] / 64;
    const int G = in_sizes[1] / 2;
    const int E = in_sizes[2] / 2;
    const int L = in_sizes[4] / (126 * 128);

    char* ws = (char*)d_ws;
    size_t off = 0;
    auto alloc = [&](size_t bytes) -> char* {
        char* p = ws + off;
        off += (bytes + 511) & ~(size_t)511;
        return p;
    };
    f16*    PQ     = (f16*)alloc((size_t)N * 256 * 2);
    float4* C      = (float4*)alloc((size_t)N * 16);
    float*  x1     = (float*)alloc((size_t)N * 64 * 4);
    float*  x2     = (float*)alloc((size_t)N * 64 * 4);
    int*    srcs   = (int*)alloc((size_t)E * 4);
    int*    dsts   = (int*)alloc((size_t)E * 4);
    int*    deg    = (int*)alloc((size_t)N * 4);
    int*    rowst  = (int*)alloc((size_t)N * 4);
    int*    cursor = (int*)alloc((size_t)N * 4);
    int*    bsum   = (int*)alloc(4096);
    int*    boff   = (int*)alloc(4096);
    f16*    B1T    = (f16*)alloc((size_t)L * 256 * 64 * 2);
    f16*    W2T    = (f16*)alloc((size_t)L * 128 * 128 * 2);
    f16*    W3T    = (f16*)alloc((size_t)L * 64 * 128 * 2);
    float*  w1c    = (float*)alloc((size_t)L * 128 * 4);
    float*  pooled = (float*)alloc((size_t)G * 194 * 4);
    (void)ws_size;
    (void)n_in;
    (void)out_size;

    hipMemsetAsync(deg, 0, (size_t)N * 4, stream);
    hipMemsetAsync(cursor, 0, (size_t)N * 4, stream);
    hipMemsetAsync(x1, 0, (size_t)N * 64 * 4, stream);
    hipMemsetAsync(x2, 0, (size_t)N * 64 * 4, stream);

    {
        int total = L * (16384 + 16384 + 8192 + 128);
        prep_kernel<<<(total + 255) / 256, 256, 0, stream>>>(W1, W2, W3, B1T, W2T, W3T, w1c, L, total);
    }
    hist_kernel<<<(E + 255) / 256, 256, 0, stream>>>(ei, deg, E);
    int NB = (N + 255) / 256;
    scan_part<<<NB, 256, 0, stream>>>(deg, bsum, N);
    scan_mid<<<1, 512, 0, stream>>>(bsum, boff, NB);
    scan_final<<<NB, 256, 0, stream>>>(deg, boff, rowst, N);
    scatter_kernel<<<(E + 255) / 256, 256, 0, stream>>>(ei, rowst, cursor, srcs, dsts, E);

    const float* xcur = x;
    const int etiles = (E + 63) / 64;
    const int ntiles_node = (N + 63) / 64;
    for (int l = 0; l < L; l++) {
        node_kernel<<<768, 256, 0, stream>>>(xcur, B1T + (size_t)l * 16384, b1 + l * 128,
                                             PQ, C, N, ntiles_node);
        float* xo = (l & 1) ? x2 : x1;
        edge_kernel<<<768, 256, 0, stream>>>(PQ, C, srcs, dsts,
                                             W2T + (size_t)l * 16384, W3T + (size_t)l * 8192,
                                             w1c + l * 128, b2 + l * 128, b3 + l * 64,
                                             xo, E, etiles);
        xcur = xo;
    }
    pool_kernel<<<G, 256, 0, stream>>>(xcur, u, pooled, N, G);
    head_kernel<<<G, 64, 0, stream>>>(pooled, LW1, Lb1, LW2, Lb2, LW3, Lb3, (float*)d_out, G);
}